// Round 1
// baseline (215.490 us; speedup 1.0000x reference)
//
#include <hip/hip_runtime.h>
#include <math.h>

#define IGN 255
constexpr int NC = 19;
constexpr int HWsz = 512 * 1024;
constexpr int NPIX = 8 * HWsz;

struct Ctl {
  double total;       // kept-loss sum (double atomics)
  unsigned n_valid;
  unsigned k;         // remaining rank during radix select
  unsigned prefix;    // accumulated key prefix
  unsigned cnt;       // kept count
  float thr;          // selected threshold value
  unsigned pad;
};

constexpr size_t HIST_OFF = 256;        // 2048 x u32 histogram
constexpr size_t LOSS_OFF = 16384;      // NPIX floats

__device__ inline unsigned flip_key(unsigned u) {
  // monotone map: float total order -> unsigned order
  unsigned mask = (unsigned)((int)u >> 31) | 0x80000000u;
  return u ^ mask;
}
__device__ inline float unflip_val(unsigned k) {
  unsigned u = (k & 0x80000000u) ? (k ^ 0x80000000u) : ~k;
  return __uint_as_float(u);
}

__global__ void k_init(unsigned char* ws) {
  Ctl* ctl = (Ctl*)ws;
  unsigned* hist = (unsigned*)(ws + HIST_OFF);
  int t = threadIdx.x;
  if (t == 0) {
    ctl->total = 0.0; ctl->n_valid = 0; ctl->k = 0;
    ctl->prefix = 0; ctl->cnt = 0; ctl->thr = 0.f;
  }
  for (int i = t; i < 2048; i += 256) hist[i] = 0;
}

__global__ __launch_bounds__(256) void k_loss(const float* __restrict__ logits,
                                              const int* __restrict__ labels,
                                              unsigned char* __restrict__ ws) {
  Ctl* ctl = (Ctl*)ws;
  float* loss = (float*)(ws + LOSS_OFF);
  int tid = blockIdx.x * 256 + threadIdx.x;
  int n0 = tid * 4;                       // 4 pixels per thread
  int b = n0 / HWsz;
  int hw = n0 - b * HWsz;
  const float* base = logits + (size_t)(b * NC) * HWsz + hw;

  float4 v[NC];
#pragma unroll
  for (int c = 0; c < NC; ++c)
    v[c] = *reinterpret_cast<const float4*>(base + (size_t)c * HWsz);

  float4 m = v[0];
#pragma unroll
  for (int c = 1; c < NC; ++c) {
    m.x = fmaxf(m.x, v[c].x); m.y = fmaxf(m.y, v[c].y);
    m.z = fmaxf(m.z, v[c].z); m.w = fmaxf(m.w, v[c].w);
  }
  float4 s = make_float4(0.f, 0.f, 0.f, 0.f);
#pragma unroll
  for (int c = 0; c < NC; ++c) {
    s.x += __expf(v[c].x - m.x); s.y += __expf(v[c].y - m.y);
    s.z += __expf(v[c].z - m.z); s.w += __expf(v[c].w - m.w);
  }
  float4 lse;
  lse.x = m.x + __logf(s.x); lse.y = m.y + __logf(s.y);
  lse.z = m.z + __logf(s.z); lse.w = m.w + __logf(s.w);

  int4 lab = *reinterpret_cast<const int4*>(labels + n0);
  float4 vl = make_float4(0.f, 0.f, 0.f, 0.f);
#pragma unroll
  for (int c = 0; c < NC; ++c) {         // static-index gather of v[label]
    vl.x = (lab.x == c) ? v[c].x : vl.x;
    vl.y = (lab.y == c) ? v[c].y : vl.y;
    vl.z = (lab.z == c) ? v[c].z : vl.z;
    vl.w = (lab.w == c) ? v[c].w : vl.w;
  }
  float4 out;
  unsigned cnt = 0;
  out.x = (lab.x == IGN) ? -INFINITY : (lse.x - vl.x); cnt += (lab.x != IGN);
  out.y = (lab.y == IGN) ? -INFINITY : (lse.y - vl.y); cnt += (lab.y != IGN);
  out.z = (lab.z == IGN) ? -INFINITY : (lse.z - vl.z); cnt += (lab.z != IGN);
  out.w = (lab.w == IGN) ? -INFINITY : (lse.w - vl.w); cnt += (lab.w != IGN);
  *reinterpret_cast<float4*>(loss + n0) = out;

  __shared__ unsigned red[256];
  red[threadIdx.x] = cnt;
  __syncthreads();
  for (int s2 = 128; s2 > 0; s2 >>= 1) {
    if (threadIdx.x < s2) red[threadIdx.x] += red[threadIdx.x + s2];
    __syncthreads();
  }
  if (threadIdx.x == 0 && red[0]) atomicAdd(&ctl->n_valid, red[0]);
}

template <int PASS>
__global__ __launch_bounds__(256) void k_hist(unsigned char* __restrict__ ws) {
  const unsigned* keys = (const unsigned*)(ws + LOSS_OFF);
  unsigned* hist = (unsigned*)(ws + HIST_OFF);
  const Ctl* ctl = (const Ctl*)ws;
  __shared__ unsigned lh[2048];
  for (int i = threadIdx.x; i < 2048; i += 256) lh[i] = 0;
  unsigned prefix = ctl->prefix;
  __syncthreads();

  unsigned idx0 = blockIdx.x * 512 + threadIdx.x;   // uint4 index
#pragma unroll
  for (int i = 0; i < 2; ++i) {
    uint4 u = reinterpret_cast<const uint4*>(keys)[idx0 + i * 256];
    unsigned a[4] = {u.x, u.y, u.z, u.w};
#pragma unroll
    for (int j = 0; j < 4; ++j) {
      unsigned key = flip_key(a[j]);
      if (PASS == 0) {
        atomicAdd(&lh[key >> 21], 1u);
      } else if (PASS == 1) {
        if ((key >> 21) == prefix) atomicAdd(&lh[(key >> 10) & 0x7FFu], 1u);
      } else {
        if ((key >> 10) == prefix) atomicAdd(&lh[key & 0x3FFu], 1u);
      }
    }
  }
  __syncthreads();
  for (int i = threadIdx.x; i < 2048; i += 256)
    if (lh[i]) atomicAdd(&hist[i], lh[i]);
}

template <int PASS>
__global__ __launch_bounds__(256) void k_scan(unsigned char* __restrict__ ws) {
  constexpr int NB = (PASS == 2) ? 1024 : 2048;
  constexpr int BPT = NB / 256;
  Ctl* ctl = (Ctl*)ws;
  unsigned* hist = (unsigned*)(ws + HIST_OFF);
  int t = threadIdx.x;

  unsigned k;
  if (PASS == 0) {
    unsigned nv = ctl->n_valid;
    int nk = (int)(0.3f * (float)nv);
    int mk = (100000 < (int)nv) ? 100000 : (int)nv;
    if (nk < mk) nk = mk;
    if (nk > (int)nv) nk = (int)nv;
    k = (unsigned)nk;
  } else {
    k = ctl->k;
  }

  unsigned local[BPT];
  unsigned lsum = 0;
#pragma unroll
  for (int j = 0; j < BPT; ++j) {
    unsigned v = hist[t * BPT + j];
    hist[t * BPT + j] = 0;               // re-zero for next pass
    local[j] = v;
    lsum += v;
  }
  __shared__ unsigned ts[256];
  ts[t] = lsum;
  __syncthreads();
  // inclusive suffix scan (toward higher thread index)
  for (int off = 1; off < 256; off <<= 1) {
    unsigned add = (t + off < 256) ? ts[t + off] : 0u;
    __syncthreads();
    ts[t] += add;
    __syncthreads();
  }
  unsigned above = ts[t] - lsum;         // count in bins strictly above my range
  if (k > 0) {
#pragma unroll
    for (int j = BPT - 1; j >= 0; --j) {
      unsigned cbin = local[j];
      unsigned tot = above + cbin;
      if (above < k && tot >= k) {
        unsigned bin = (unsigned)(t * BPT + j);
        unsigned kk = k - above;
        if (PASS == 0) {
          ctl->prefix = bin; ctl->k = kk;
        } else if (PASS == 1) {
          ctl->prefix = (ctl->prefix << 11) | bin; ctl->k = kk;
        } else {
          unsigned key = (ctl->prefix << 10) | bin;
          ctl->thr = unflip_val(key);
        }
      }
      above = tot;
    }
  }
}

__global__ __launch_bounds__(256) void k_final(unsigned char* __restrict__ ws) {
  const float* loss = (const float*)(ws + LOSS_OFF);
  Ctl* ctl = (Ctl*)ws;
  float thr = ctl->thr;
  unsigned idx0 = blockIdx.x * 512 + threadIdx.x;
  float s = 0.f;
  unsigned c = 0;
#pragma unroll
  for (int i = 0; i < 2; ++i) {
    float4 v = reinterpret_cast<const float4*>(loss)[idx0 + i * 256];
    if (v.x >= thr) { s += v.x; c++; }
    if (v.y >= thr) { s += v.y; c++; }
    if (v.z >= thr) { s += v.z; c++; }
    if (v.w >= thr) { s += v.w; c++; }
  }
  double sd = (double)s;
  for (int off = 32; off > 0; off >>= 1) {
    sd += __shfl_down(sd, off);
    c += __shfl_down(c, off);
  }
  __shared__ double sred[4];
  __shared__ unsigned cred[4];
  int wave = threadIdx.x >> 6, lane = threadIdx.x & 63;
  if (lane == 0) { sred[wave] = sd; cred[wave] = c; }
  __syncthreads();
  if (threadIdx.x == 0) {
    double st = sred[0] + sred[1] + sred[2] + sred[3];
    unsigned ct = cred[0] + cred[1] + cred[2] + cred[3];
    atomicAdd(&ctl->total, st);
    atomicAdd(&ctl->cnt, ct);
  }
}

__global__ void k_fin(unsigned char* __restrict__ ws, float* __restrict__ out) {
  if (threadIdx.x == 0) {
    Ctl* ctl = (Ctl*)ws;
    float r = 0.f;
    if (ctl->n_valid != 0) {
      unsigned c = ctl->cnt; if (c < 1u) c = 1u;
      r = (float)(ctl->total / (double)c);
    }
    out[0] = r;
  }
}

extern "C" void kernel_launch(void* const* d_in, const int* in_sizes, int n_in,
                              void* d_out, int out_size, void* d_ws, size_t ws_size,
                              hipStream_t stream) {
  const float* logits = (const float*)d_in[0];
  const int* labels = (const int*)d_in[1];
  float* out = (float*)d_out;
  unsigned char* ws = (unsigned char*)d_ws;

  hipLaunchKernelGGL(k_init, dim3(1), dim3(256), 0, stream, ws);
  hipLaunchKernelGGL(k_loss, dim3(NPIX / 4 / 256), dim3(256), 0, stream, logits, labels, ws);
  hipLaunchKernelGGL((k_hist<0>), dim3(NPIX / 8 / 256), dim3(256), 0, stream, ws);
  hipLaunchKernelGGL((k_scan<0>), dim3(1), dim3(256), 0, stream, ws);
  hipLaunchKernelGGL((k_hist<1>), dim3(NPIX / 8 / 256), dim3(256), 0, stream, ws);
  hipLaunchKernelGGL((k_scan<1>), dim3(1), dim3(256), 0, stream, ws);
  hipLaunchKernelGGL((k_hist<2>), dim3(NPIX / 8 / 256), dim3(256), 0, stream, ws);
  hipLaunchKernelGGL((k_scan<2>), dim3(1), dim3(256), 0, stream, ws);
  hipLaunchKernelGGL(k_final, dim3(NPIX / 8 / 256), dim3(256), 0, stream, ws);
  hipLaunchKernelGGL(k_fin, dim3(1), dim3(64), 0, stream, ws, out);
}

// Round 3
// 215.149 us; speedup vs baseline: 1.0016x; 1.0016x over previous
//
#include <hip/hip_runtime.h>
#include <math.h>

#define IGN 255
constexpr int NC = 19;
constexpr int HWsz = 512 * 1024;
constexpr int NPIX = 8 * HWsz;

typedef float v4f __attribute__((ext_vector_type(4)));
typedef int v4i __attribute__((ext_vector_type(4)));
typedef unsigned v4u __attribute__((ext_vector_type(4)));

struct Ctl {
  double total;
  unsigned n_valid, cnt, done, pad;
};

constexpr size_t H0 = 256;               // 2048 u32
constexpr size_t H1 = H0 + 2048 * 4;     // 2048 u32
constexpr size_t H2 = H1 + 2048 * 4;     // 1024 u32
constexpr size_t LOSS_OFF = 65536;       // NPIX floats

__device__ inline unsigned flip_key(unsigned u) {
  unsigned mask = (unsigned)((int)u >> 31) | 0x80000000u;
  return u ^ mask;
}
__device__ inline float unflip_val(unsigned k) {
  unsigned u = (k & 0x80000000u) ? (k ^ 0x80000000u) : ~k;
  return __uint_as_float(u);
}
__device__ inline unsigned compute_k(unsigned nv) {
  int nk = (int)(0.3f * (float)nv);
  int mk = (100000 < (int)nv) ? 100000 : (int)nv;
  if (nk < mk) nk = mk;
  if (nk > (int)nv) nk = (int)nv;
  return (unsigned)nk;
}

// Per-block redundant selection scan over a global histogram.
template <int NB>
__device__ inline void selscan(const unsigned* __restrict__ hist, unsigned k,
                               unsigned& bin, unsigned& kk) {
  constexpr int BPT = NB / 256;
  __shared__ unsigned ts[256];
  __shared__ unsigned bb[2];
  int t = threadIdx.x;
  unsigned local[BPT];
  unsigned lsum = 0;
#pragma unroll
  for (int j = 0; j < BPT; ++j) { local[j] = hist[t * BPT + j]; lsum += local[j]; }
  ts[t] = lsum;
  __syncthreads();
  for (int off = 1; off < 256; off <<= 1) {
    unsigned add = (t + off < 256) ? ts[t + off] : 0u;
    __syncthreads();
    ts[t] += add;
    __syncthreads();
  }
  unsigned above = ts[t] - lsum;
  if (t == 0) { bb[0] = 0xFFFFFFFFu; bb[1] = 0u; }
  __syncthreads();
  if (k > 0) {
#pragma unroll
    for (int j = BPT - 1; j >= 0; --j) {
      unsigned cb = local[j];
      unsigned tot = above + cb;
      if (above < k && tot >= k) { bb[0] = (unsigned)(t * BPT + j); bb[1] = k - above; }
      above = tot;
    }
  }
  __syncthreads();
  bin = bb[0];
  kk = bb[1];
  __syncthreads();
}

__global__ void k_init(unsigned char* ws) {
  Ctl* ctl = (Ctl*)ws;
  unsigned* h = (unsigned*)(ws + H0);
  int t = threadIdx.x;
  if (t == 0) { ctl->total = 0.0; ctl->n_valid = 0; ctl->cnt = 0; ctl->done = 0; }
  for (int i = t; i < 5120; i += 256) h[i] = 0;
}

__global__ __launch_bounds__(256) void k_loss(const float* __restrict__ logits,
                                              const int* __restrict__ labels,
                                              unsigned char* __restrict__ ws) {
  Ctl* ctl = (Ctl*)ws;
  float* loss = (float*)(ws + LOSS_OFF);
  unsigned* h0 = (unsigned*)(ws + H0);
  __shared__ unsigned lh[2048];
  __shared__ unsigned red[256];
  for (int i = threadIdx.x; i < 2048; i += 256) lh[i] = 0;
  __syncthreads();

  int tid = blockIdx.x * 256 + threadIdx.x;
  int n0 = tid * 4;
  int b = n0 >> 19;                       // / HWsz
  int hw = n0 & (HWsz - 1);
  const float* base = logits + (size_t)(b * NC) * HWsz + hw;

  v4f v[NC];
#pragma unroll
  for (int c = 0; c < NC; ++c)
    v[c] = __builtin_nontemporal_load(reinterpret_cast<const v4f*>(base + (size_t)c * HWsz));

  v4f m = v[0];
#pragma unroll
  for (int c = 1; c < NC; ++c) {
    m[0] = fmaxf(m[0], v[c][0]); m[1] = fmaxf(m[1], v[c][1]);
    m[2] = fmaxf(m[2], v[c][2]); m[3] = fmaxf(m[3], v[c][3]);
  }
  v4f s = (v4f)(0.f);
#pragma unroll
  for (int c = 0; c < NC; ++c) {
    s[0] += __expf(v[c][0] - m[0]); s[1] += __expf(v[c][1] - m[1]);
    s[2] += __expf(v[c][2] - m[2]); s[3] += __expf(v[c][3] - m[3]);
  }
  v4f lse;
  lse[0] = m[0] + __logf(s[0]); lse[1] = m[1] + __logf(s[1]);
  lse[2] = m[2] + __logf(s[2]); lse[3] = m[3] + __logf(s[3]);

  v4i lab = *reinterpret_cast<const v4i*>(labels + n0);
  v4f vl = (v4f)(0.f);
#pragma unroll
  for (int c = 0; c < NC; ++c) {
    vl[0] = (lab[0] == c) ? v[c][0] : vl[0];
    vl[1] = (lab[1] == c) ? v[c][1] : vl[1];
    vl[2] = (lab[2] == c) ? v[c][2] : vl[2];
    vl[3] = (lab[3] == c) ? v[c][3] : vl[3];
  }
  v4f out;
  unsigned cnt = 0;
  out[0] = (lab[0] == IGN) ? -INFINITY : (lse[0] - vl[0]); cnt += (lab[0] != IGN);
  out[1] = (lab[1] == IGN) ? -INFINITY : (lse[1] - vl[1]); cnt += (lab[1] != IGN);
  out[2] = (lab[2] == IGN) ? -INFINITY : (lse[2] - vl[2]); cnt += (lab[2] != IGN);
  out[3] = (lab[3] == IGN) ? -INFINITY : (lse[3] - vl[3]); cnt += (lab[3] != IGN);
  *reinterpret_cast<v4f*>(loss + n0) = out;

  // fused hist pass 0 (top 11 bits of flipped key)
  atomicAdd(&lh[flip_key(__float_as_uint(out[0])) >> 21], 1u);
  atomicAdd(&lh[flip_key(__float_as_uint(out[1])) >> 21], 1u);
  atomicAdd(&lh[flip_key(__float_as_uint(out[2])) >> 21], 1u);
  atomicAdd(&lh[flip_key(__float_as_uint(out[3])) >> 21], 1u);

  red[threadIdx.x] = cnt;
  __syncthreads();
  for (int s2 = 128; s2 > 0; s2 >>= 1) {
    if (threadIdx.x < s2) red[threadIdx.x] += red[threadIdx.x + s2];
    __syncthreads();
  }
  if (threadIdx.x == 0 && red[0]) atomicAdd(&ctl->n_valid, red[0]);
  for (int i = threadIdx.x; i < 2048; i += 256)
    if (lh[i]) atomicAdd(&h0[i], lh[i]);
}

__global__ __launch_bounds__(256) void k_hist1(unsigned char* __restrict__ ws) {
  Ctl* ctl = (Ctl*)ws;
  const unsigned* keys = (const unsigned*)(ws + LOSS_OFF);
  unsigned* h0 = (unsigned*)(ws + H0);
  unsigned* h1 = (unsigned*)(ws + H1);
  __shared__ unsigned lh[2048];
  unsigned k0 = compute_k(ctl->n_valid);
  unsigned p0, k1;
  selscan<2048>(h0, k0, p0, k1);
  for (int i = threadIdx.x; i < 2048; i += 256) lh[i] = 0;
  __syncthreads();

  unsigned idx0 = blockIdx.x * 512 + threadIdx.x;
#pragma unroll
  for (int i = 0; i < 2; ++i) {
    v4u u = reinterpret_cast<const v4u*>(keys)[idx0 + i * 256];
#pragma unroll
    for (int j = 0; j < 4; ++j) {
      unsigned key = flip_key(u[j]);
      if ((key >> 21) == p0) atomicAdd(&lh[(key >> 10) & 0x7FFu], 1u);
    }
  }
  __syncthreads();
  for (int i = threadIdx.x; i < 2048; i += 256)
    if (lh[i]) atomicAdd(&h1[i], lh[i]);
}

__global__ __launch_bounds__(256) void k_hist2(unsigned char* __restrict__ ws) {
  Ctl* ctl = (Ctl*)ws;
  const unsigned* keys = (const unsigned*)(ws + LOSS_OFF);
  unsigned* h0 = (unsigned*)(ws + H0);
  unsigned* h1 = (unsigned*)(ws + H1);
  unsigned* h2 = (unsigned*)(ws + H2);
  __shared__ unsigned lh[1024];
  unsigned k0 = compute_k(ctl->n_valid);
  unsigned p0, k1, p1, k2;
  selscan<2048>(h0, k0, p0, k1);
  selscan<2048>(h1, k1, p1, k2);
  unsigned pp = (p0 << 11) | p1;
  for (int i = threadIdx.x; i < 1024; i += 256) lh[i] = 0;
  __syncthreads();

  unsigned idx0 = blockIdx.x * 512 + threadIdx.x;
#pragma unroll
  for (int i = 0; i < 2; ++i) {
    v4u u = reinterpret_cast<const v4u*>(keys)[idx0 + i * 256];
#pragma unroll
    for (int j = 0; j < 4; ++j) {
      unsigned key = flip_key(u[j]);
      if ((key >> 10) == pp) atomicAdd(&lh[key & 0x3FFu], 1u);
    }
  }
  __syncthreads();
  for (int i = threadIdx.x; i < 1024; i += 256)
    if (lh[i]) atomicAdd(&h2[i], lh[i]);
}

__global__ __launch_bounds__(256) void k_final(unsigned char* __restrict__ ws,
                                               float* __restrict__ out) {
  Ctl* ctl = (Ctl*)ws;
  const float* loss = (const float*)(ws + LOSS_OFF);
  unsigned* h0 = (unsigned*)(ws + H0);
  unsigned* h1 = (unsigned*)(ws + H1);
  unsigned* h2 = (unsigned*)(ws + H2);
  unsigned k0 = compute_k(ctl->n_valid);
  unsigned p0, k1, p1, k2, b2, kf;
  selscan<2048>(h0, k0, p0, k1);
  selscan<2048>(h1, k1, p1, k2);
  selscan<1024>(h2, k2, b2, kf);
  float thr = INFINITY;
  if (k0 > 0) thr = unflip_val((((p0 << 11) | p1) << 10) | b2);

  unsigned idx0 = blockIdx.x * 512 + threadIdx.x;
  float s = 0.f;
  unsigned c = 0;
#pragma unroll
  for (int i = 0; i < 2; ++i) {
    v4f v = reinterpret_cast<const v4f*>(loss)[idx0 + i * 256];
    if (v[0] >= thr) { s += v[0]; c++; }
    if (v[1] >= thr) { s += v[1]; c++; }
    if (v[2] >= thr) { s += v[2]; c++; }
    if (v[3] >= thr) { s += v[3]; c++; }
  }
  double sd = (double)s;
  for (int off = 32; off > 0; off >>= 1) {
    sd += __shfl_down(sd, off);
    c += __shfl_down(c, off);
  }
  __shared__ double sred[4];
  __shared__ unsigned cred[4];
  int wave = threadIdx.x >> 6, lane = threadIdx.x & 63;
  if (lane == 0) { sred[wave] = sd; cred[wave] = c; }
  __syncthreads();
  if (threadIdx.x == 0) {
    double st = sred[0] + sred[1] + sred[2] + sred[3];
    unsigned ct = cred[0] + cred[1] + cred[2] + cred[3];
    atomicAdd(&ctl->total, st);
    atomicAdd(&ctl->cnt, ct);
    __threadfence();
    unsigned prev = atomicAdd(&ctl->done, 1u);
    if (prev == gridDim.x - 1) {
      double tt = atomicAdd(&ctl->total, 0.0);
      unsigned cc = atomicAdd(&ctl->cnt, 0u);
      float r = 0.f;
      if (ctl->n_valid != 0) {
        if (cc < 1u) cc = 1u;
        r = (float)(tt / (double)cc);
      }
      out[0] = r;
    }
  }
}

extern "C" void kernel_launch(void* const* d_in, const int* in_sizes, int n_in,
                              void* d_out, int out_size, void* d_ws, size_t ws_size,
                              hipStream_t stream) {
  const float* logits = (const float*)d_in[0];
  const int* labels = (const int*)d_in[1];
  float* out = (float*)d_out;
  unsigned char* ws = (unsigned char*)d_ws;

  hipLaunchKernelGGL(k_init, dim3(1), dim3(256), 0, stream, ws);
  hipLaunchKernelGGL(k_loss, dim3(NPIX / 4 / 256), dim3(256), 0, stream, logits, labels, ws);
  hipLaunchKernelGGL(k_hist1, dim3(NPIX / 8 / 256), dim3(256), 0, stream, ws);
  hipLaunchKernelGGL(k_hist2, dim3(NPIX / 8 / 256), dim3(256), 0, stream, ws);
  hipLaunchKernelGGL(k_final, dim3(NPIX / 8 / 256), dim3(256), 0, stream, ws, out);
}